// Round 1
// baseline (585.715 us; speedup 1.0000x reference)
//
#include <hip/hip_runtime.h>
#include <math.h>

#define NB 32
#define NQ 16
#define NP 196
#define OUTW 3840

// ---------- resize weights (jax.image.resize, triangle kernel, antialias=True) ----------
template<int N>
__device__ __forceinline__ int calc_w(int i, float* w, int& lo) {
  constexpr float inv = (float)N / 14.0f;          // 4, 2, 0.5 — exact
  constexpr float ks  = (inv > 1.0f) ? inv : 1.0f; // kernel_scale = max(inv_scale, 1)
  constexpr float rks = 1.0f / ks;
  float sf = ((float)i + 0.5f) * inv - 0.5f;
  int l = (int)ceilf(sf - ks);
  int h = (int)floorf(sf + ks);
  if (l < 0) l = 0;
  if (h > N - 1) h = N - 1;
  int n = h - l + 1;
  float sum = 0.f;
  for (int k = 0; k < n; ++k) {
    float t = 1.0f - fabsf((float)(l + k) - sf) * rks;
    t = t > 0.f ? t : 0.f;
    w[k] = t; sum += t;
  }
  float r = 1.0f / sum;
  for (int k = 0; k < n; ++k) w[k] *= r;
  lo = l;
  return n;
}

// ---------- K0: bilinear resize NxN -> 14x14, one block per (sample, channel) plane ----------
template<int N>
__global__ void k_resize(const float* __restrict__ x, float* __restrict__ xr) {
  __shared__ float plane[N * N];
  const int bid = blockIdx.x;        // s*cm + c  (linear)
  const int t = threadIdx.x;
  const float* src = x + (size_t)bid * (N * N);
  for (int idx = t; idx < N * N; idx += 256) plane[idx] = src[idx];
  __syncthreads();
  if (t < NP) {
    int oy = t / 14, ox = t % 14;
    float wy[8], wx[8];
    int ly, lx;
    int ny = calc_w<N>(oy, wy, ly);
    int nx = calc_w<N>(ox, wx, lx);
    float acc = 0.f;
    for (int a = 0; a < ny; ++a) {
      const float* row = plane + (ly + a) * N + lx;
      float h = 0.f;
      for (int b = 0; b < nx; ++b) h = fmaf(wx[b], row[b], h);
      acc = fmaf(wy[a], h, acc);
    }
    xr[(size_t)bid * NP + t] = acc;
  }
}

// ---------- K1: per (sample, 64-channel chunk): partial {sum, sumsq, Y=W*Xr} ----------
#define CC 64
__global__ void k_stats(const float* __restrict__ xr, const float* __restrict__ W,
                        float* __restrict__ part, int cm, int nch) {
  __shared__ float tile[CC * NP];   // 49 KB
  __shared__ float wl[NQ * CC];     // 4 KB
  const int t = threadIdx.x;
  const int s = blockIdx.x / nch;
  const int ch = blockIdx.x % nch;
  const int c0 = ch * CC;
  const float* src = xr + ((size_t)s * cm + c0) * NP;
  for (int idx = t; idx < CC * NP; idx += 256) tile[idx] = src[idx];
  for (int idx = t; idx < NQ * CC; idx += 256) {
    int q = idx / CC, cc = idx % CC;
    wl[idx] = W[q * cm + c0 + cc];
  }
  __syncthreads();
  if (t < NP) {
    float s1 = 0.f, s2 = 0.f, y[NQ];
#pragma unroll
    for (int q = 0; q < NQ; ++q) y[q] = 0.f;
    for (int cc = 0; cc < CC; ++cc) {
      float v = tile[cc * NP + t];
      s1 += v; s2 = fmaf(v, v, s2);
#pragma unroll
      for (int q = 0; q < NQ; ++q) y[q] = fmaf(wl[q * CC + cc], v, y[q]);
    }
    float* pb = part + ((size_t)(s * nch + ch) * 18) * NP + t;
    pb[0] = s1;
    pb[NP] = s2;
#pragma unroll
    for (int q = 0; q < NQ; ++q) pb[(size_t)(2 + q) * NP] = y[q];
  }
}

// ---------- K2: per sample: combine partials, mu/rsd, H=sigmoid, G=HH^T, invert G ----------
__global__ void k_head(const float* __restrict__ part, const float* __restrict__ W,
                       float* __restrict__ murs, float* __restrict__ hws,
                       float* __restrict__ mws, int cm, int nch) {
  __shared__ float red[256];
  __shared__ float wsum[NQ];
  __shared__ float Hl[NQ * NP];     // 12.5 KB
  __shared__ float aug[16 * 33];
  const int t = threadIdx.x;
  const int s = blockIdx.x;

  // wsum[q] = sum_c W[q][c]
  {
    int q = t >> 4, l = t & 15;
    float p = 0.f;
    for (int c = l; c < cm; c += 16) p += W[q * cm + c];
    red[t] = p;
  }
  __syncthreads();
  if (t < NQ) {
    float v = 0.f;
    for (int k = 0; k < 16; ++k) v += red[t * 16 + k];
    wsum[t] = v;
  }
  __syncthreads();

  // combine partials, compute mu/rsd and H
  if (t < NP) {
    float s1 = 0.f, s2 = 0.f, y[NQ];
#pragma unroll
    for (int q = 0; q < NQ; ++q) y[q] = 0.f;
    for (int ch = 0; ch < nch; ++ch) {
      const float* pb = part + ((size_t)(s * nch + ch) * 18) * NP + t;
      s1 += pb[0];
      s2 += pb[NP];
#pragma unroll
      for (int q = 0; q < NQ; ++q) y[q] += pb[(size_t)(2 + q) * NP];
    }
    float mu = s1 / (float)cm;
    float var = (s2 - s1 * mu) / (float)(cm - 1);
    float rsd = (var > 0.f) ? (1.0f / sqrtf(var)) : 0.f;
    murs[((size_t)s * 2) * NP + t] = mu;
    murs[((size_t)s * 2 + 1) * NP + t] = rsd;
#pragma unroll
    for (int q = 0; q < NQ; ++q) {
      float arg = (y[q] - wsum[q] * mu) * rsd;
      Hl[q * NP + t] = 1.0f / (1.0f + expf(-arg));
    }
  }
  __syncthreads();

  // write H to global for K3
  for (int idx = t; idx < NQ * NP; idx += 256)
    hws[(size_t)s * NQ * NP + idx] = Hl[idx];

  // G = H H^T  (16x16, thread = (q1,q2))
  {
    int q1 = t >> 4, q2 = t & 15;
    float g = 0.f;
    for (int p = 0; p < NP; ++p) g = fmaf(Hl[q1 * NP + p], Hl[q2 * NP + p], g);
    aug[q1 * 33 + q2] = g;
    aug[q1 * 33 + 16 + q2] = (q1 == q2) ? 1.0f : 0.f;
  }
  __syncthreads();

  // Gauss-Jordan (G is SPD, no pivoting)
  for (int k = 0; k < 16; ++k) {
    float rpv = 1.0f / aug[k * 33 + k];
    __syncthreads();
    if (t < 32) aug[k * 33 + t] *= rpv;
    __syncthreads();
    int i = t >> 4, j = t & 15;
    float f = aug[i * 33 + k];
    __syncthreads();
    if (i != k) {
      aug[i * 33 + j]      -= f * aug[k * 33 + j];
      aug[i * 33 + 16 + j] -= f * aug[k * 33 + 16 + j];
    }
    __syncthreads();
  }
  {
    int i = t >> 4, j = t & 15;
    mws[(size_t)s * 256 + t] = aug[i * 33 + 16 + j];
  }
}

// ---------- K3: per (sample, 32-channel chunk): C = Xn H^T, b = C M, out = var(b) ----------
#define CC3 32
__global__ void k_var(const float* __restrict__ xr, const float* __restrict__ murs,
                      const float* __restrict__ hws, const float* __restrict__ mws,
                      float* __restrict__ out, int cm, int ooff) {
  __shared__ float tile[CC3 * NP];  // 24.5 KB
  __shared__ float Hl[NQ * NP];     // 12.5 KB
  __shared__ float mu[NP], rsd[NP];
  __shared__ float Ml[256];
  __shared__ float cmat[CC3 * NQ];
  const int t = threadIdx.x;        // 512 threads
  const int nch = cm / CC3;
  const int s = blockIdx.x / nch;
  const int ch = blockIdx.x % nch;
  const int c0 = ch * CC3;
  const float* src = xr + ((size_t)s * cm + c0) * NP;
  for (int idx = t; idx < CC3 * NP; idx += 512) tile[idx] = src[idx];
  for (int idx = t; idx < NQ * NP; idx += 512) Hl[idx] = hws[(size_t)s * NQ * NP + idx];
  for (int idx = t; idx < NP; idx += 512) {
    mu[idx]  = murs[((size_t)s * 2) * NP + idx];
    rsd[idx] = murs[((size_t)s * 2 + 1) * NP + idx];
  }
  if (t < 256) Ml[t] = mws[(size_t)s * 256 + t];
  __syncthreads();
  for (int idx = t; idx < CC3 * NP; idx += 512) {
    int p = idx % NP;
    tile[idx] = (tile[idx] - mu[p]) * rsd[p];
  }
  __syncthreads();
  {
    int cc = t >> 4, q = t & 15;
    const float* tr = tile + cc * NP;
    const float* hr = Hl + q * NP;
    float acc = 0.f;
    for (int p = 0; p < NP; ++p) acc = fmaf(tr[p], hr[p], acc);
    cmat[cc * NQ + q] = acc;
  }
  __syncthreads();
  if (t < CC3) {
    float b[NQ];
    float mean = 0.f;
#pragma unroll
    for (int j = 0; j < NQ; ++j) {
      float v = 0.f;
#pragma unroll
      for (int q = 0; q < NQ; ++q) v = fmaf(cmat[t * NQ + q], Ml[q * 16 + j], v);
      b[j] = v; mean += v;
    }
    mean *= (1.0f / 16.0f);
    float var = 0.f;
#pragma unroll
    for (int j = 0; j < NQ; ++j) { float d = b[j] - mean; var = fmaf(d, d, var); }
    var *= (1.0f / 15.0f);
    out[(size_t)s * OUTW + ooff + c0 + t] = var;
  }
}

extern "C" void kernel_launch(void* const* d_in, const int* in_sizes, int n_in,
                              void* d_out, int out_size, void* d_ws, size_t ws_size,
                              hipStream_t stream) {
  const float* x0 = (const float*)d_in[0];
  const float* W0 = (const float*)d_in[1];
  const float* x1 = (const float*)d_in[2];
  const float* W1 = (const float*)d_in[3];
  const float* x2 = (const float*)d_in[4];
  const float* W2 = (const float*)d_in[5];
  const float* x3 = (const float*)d_in[6];
  const float* W3 = (const float*)d_in[7];
  float* out = (float*)d_out;
  float* ws = (float*)d_ws;

  // workspace layout (floats)
  float* xr0 = ws;                                   // 32*256*196
  float* xr1 = xr0 + (size_t)NB * 256 * NP;          // 32*512*196
  float* xr3 = xr1 + (size_t)NB * 512 * NP;          // 32*2048*196
  float* part0 = xr3 + (size_t)NB * 2048 * NP;
  size_t pl0 = (size_t)NB * 4  * 18 * NP;
  size_t pl1 = (size_t)NB * 8  * 18 * NP;
  size_t pl2 = (size_t)NB * 16 * 18 * NP;
  size_t pl3 = (size_t)NB * 32 * 18 * NP;
  float* part1 = part0 + pl0;
  float* part2 = part1 + pl1;
  float* part3 = part2 + pl2;
  float* murs = part3 + pl3;                         // [4][32][2][196]
  float* hws  = murs + (size_t)4 * NB * 2 * NP;      // [4][32][16][196]
  float* mws  = hws  + (size_t)4 * NB * NQ * NP;     // [4][32][256]

  float* murs_m[4], *hws_m[4], *mws_m[4];
  for (int m = 0; m < 4; ++m) {
    murs_m[m] = murs + (size_t)m * NB * 2 * NP;
    hws_m[m]  = hws  + (size_t)m * NB * NQ * NP;
    mws_m[m]  = mws  + (size_t)m * NB * 256;
  }

  // K0: resize (member 2 is identity -> use x2 directly)
  k_resize<56><<<NB * 256, 256, 0, stream>>>(x0, xr0);
  k_resize<28><<<NB * 512, 256, 0, stream>>>(x1, xr1);
  k_resize<7><<<NB * 2048, 256, 0, stream>>>(x3, xr3);

  // K1: stats + Y partials
  k_stats<<<NB * 4,  256, 0, stream>>>(xr0, W0, part0, 256, 4);
  k_stats<<<NB * 8,  256, 0, stream>>>(xr1, W1, part1, 512, 8);
  k_stats<<<NB * 16, 256, 0, stream>>>(x2,  W2, part2, 1024, 16);
  k_stats<<<NB * 32, 256, 0, stream>>>(xr3, W3, part3, 2048, 32);

  // K2: head (mu/rsd, H, G^-1)
  k_head<<<NB, 256, 0, stream>>>(part0, W0, murs_m[0], hws_m[0], mws_m[0], 256, 4);
  k_head<<<NB, 256, 0, stream>>>(part1, W1, murs_m[1], hws_m[1], mws_m[1], 512, 8);
  k_head<<<NB, 256, 0, stream>>>(part2, W2, murs_m[2], hws_m[2], mws_m[2], 1024, 16);
  k_head<<<NB, 256, 0, stream>>>(part3, W3, murs_m[3], hws_m[3], mws_m[3], 2048, 32);

  // K3: C GEMM + variance -> out
  k_var<<<NB * (256 / CC3),  512, 0, stream>>>(xr0, murs_m[0], hws_m[0], mws_m[0], out, 256, 0);
  k_var<<<NB * (512 / CC3),  512, 0, stream>>>(xr1, murs_m[1], hws_m[1], mws_m[1], out, 512, 256);
  k_var<<<NB * (1024 / CC3), 512, 0, stream>>>(x2,  murs_m[2], hws_m[2], mws_m[2], out, 1024, 768);
  k_var<<<NB * (2048 / CC3), 512, 0, stream>>>(xr3, murs_m[3], hws_m[3], mws_m[3], out, 2048, 1792);
  (void)in_sizes; (void)n_in; (void)out_size; (void)ws_size;
}